// Round 1
// baseline (248.803 us; speedup 1.0000x reference)
//
#include <hip/hip_runtime.h>
#include <math.h>

#define NT 100
#define NA 3
#define NC 80
#define NSCALE 3
#define NB 16

// One block per (batch, scale). Computes mean-CE partial loss for that pair.
__global__ __launch_bounds__(256) void class_loss_kernel(
    const float* __restrict__ out0,
    const float* __restrict__ out1,
    const float* __restrict__ out2,
    const float* __restrict__ targets,
    float* __restrict__ partials)
{
    const int b = blockIdx.x / NSCALE;
    const int s = blockIdx.x % NSCALE;

    const float* out;
    int H;
    if (s == 0)      { out = out0; H = 128; }
    else if (s == 1) { out = out1; H = 64;  }
    else             { out = out2; H = 32;  }
    const int W = H;
    const int HW = H * W;

    __shared__ int   s_cell[NT];
    __shared__ int   s_cls[NT];
    __shared__ int   s_wcell[NT];
    __shared__ int   s_wcls[NT];
    __shared__ int   s_n;
    __shared__ float s_wavesum[4];

    const int tid = threadIdx.x;

    // ---- Phase 1: per-target cell/class, scatter semantics ----
    if (tid < NT) {
        const float* tg = targets + ((size_t)b * NT + tid) * 5;
        float c  = tg[0];
        float x  = tg[1];
        float y  = tg[2];
        float z3 = tg[3];
        float z4 = tg[4];
        // valid = row not all-zero
        bool valid = (c != 0.0f) || (x != 0.0f) || (y != 0.0f) ||
                     (z3 != 0.0f) || (z4 != 0.0f);
        int cell = -1, cls = 0;
        if (valid) {
            int row = (int)(y * (float)H);   // trunc == .astype(int32), y in (0.01,0.99)
            int col = (int)(x * (float)W);
            cell = row * W + col;
            cls  = (int)c;
        }
        s_cell[tid] = cell;
        s_cls[tid]  = cls;
    }
    __syncthreads();

    // ---- last-write-wins dedup + deterministic serial compaction ----
    if (tid == 0) {
        int n = 0;
        for (int t = 0; t < NT; ++t) {
            int cell = s_cell[t];
            if (cell < 0) continue;
            bool win = true;
            for (int u = t + 1; u < NT; ++u) {
                if (s_cell[u] == cell) { win = false; break; }
            }
            if (win) { s_wcell[n] = cell; s_wcls[n] = s_cls[t]; ++n; }
        }
        s_n = n;
    }
    __syncthreads();

    const int n      = s_n;
    const int ntasks = n * NA;           // == number of non-IGNORE entries (denom)
    const int wave   = tid >> 6;
    const int lane   = tid & 63;

    // ---- Phase 2: one wave per (cell, anchor) task; 80-wide log-softmax ----
    float acc = 0.0f;
    for (int task = wave; task < ntasks; task += 4) {
        int wi   = task / NA;
        int a    = task - wi * NA;
        int cell = s_wcell[wi];
        int cls  = s_wcls[wi];

        // gt_flat index i in (H, W, A) order:
        int i = cell * NA + a;
        // pred row i interpreted in (A, H, W) order (reference's pairing bug):
        int a2  = i / HW;
        int rem = i - a2 * HW;
        int h2  = rem / W;
        int w2  = rem - h2 * W;

        const float* base =
            out + ((((size_t)b * NA + a2) * H + h2) * (size_t)W + w2) * (5 + NC) + 5;

        // lanes 0..63 hold elems 0..63; lanes 0..15 also hold elems 64..79
        float x0 = base[lane];
        float x1 = (lane < 16) ? base[64 + lane] : -INFINITY;

        float m = fmaxf(x0, x1);
        #pragma unroll
        for (int off = 32; off; off >>= 1) m = fmaxf(m, __shfl_xor(m, off));

        float e = __builtin_expf(x0 - m) +
                  ((lane < 16) ? __builtin_expf(x1 - m) : 0.0f);
        #pragma unroll
        for (int off = 32; off; off >>= 1) e += __shfl_xor(e, off);

        float logsum = m + __builtin_logf(e);

        float xt = (cls < 64) ? __shfl(x0, cls) : __shfl(x1, cls - 64);
        acc += (logsum - xt);   // nll; identical value on every lane
    }

    if (lane == 0) s_wavesum[wave] = acc;
    __syncthreads();

    if (tid == 0) {
        float total = s_wavesum[0] + s_wavesum[1] + s_wavesum[2] + s_wavesum[3];
        int denom = ntasks > 0 ? ntasks : 1;
        partials[blockIdx.x] = total / (float)denom;
    }
}

// Deterministic final reduction of the 48 partials.
__global__ void reduce_kernel(const float* __restrict__ partials,
                              float* __restrict__ out)
{
    if (threadIdx.x == 0 && blockIdx.x == 0) {
        float s = 0.0f;
        for (int i = 0; i < NB * NSCALE; ++i) s += partials[i];
        out[0] = s / (float)NB;   // reference divides by batch size of last scale
    }
}

extern "C" void kernel_launch(void* const* d_in, const int* in_sizes, int n_in,
                              void* d_out, int out_size, void* d_ws, size_t ws_size,
                              hipStream_t stream) {
    const float* out0    = (const float*)d_in[0];
    const float* out1    = (const float*)d_in[1];
    const float* out2    = (const float*)d_in[2];
    const float* targets = (const float*)d_in[3];

    float* partials = (float*)d_ws;   // 48 floats
    float* loss     = (float*)d_out;  // 1 float

    class_loss_kernel<<<NB * NSCALE, 256, 0, stream>>>(out0, out1, out2, targets, partials);
    reduce_kernel<<<1, 64, 0, stream>>>(partials, loss);
}

// Round 2
// 20.465 us; speedup vs baseline: 12.1577x; 12.1577x over previous
//
#include <hip/hip_runtime.h>
#include <math.h>

#define NT 100
#define NA 3
#define NC 80
#define NSCALE 3
#define NB 16
#define CH 8            // chunks per (batch, scale)
#define NPART (NB * NSCALE * CH)   // 384 partials

// Grid: NB*NSCALE*CH blocks. Each block: phase 1 (parallel dedup, cheap,
// duplicated per chunk) + phase 2 over its slice of softmax tasks.
__global__ __launch_bounds__(256) void class_loss_kernel(
    const float* __restrict__ out0,
    const float* __restrict__ out1,
    const float* __restrict__ out2,
    const float* __restrict__ targets,
    float* __restrict__ partials)
{
    const int bs    = blockIdx.x / CH;   // 0..47
    const int chunk = blockIdx.x % CH;
    const int b = bs / NSCALE;
    const int s = bs % NSCALE;

    const float* out;
    int H;
    if (s == 0)      { out = out0; H = 128; }
    else if (s == 1) { out = out1; H = 64;  }
    else             { out = out2; H = 32;  }
    const int W = H;
    const int HW = H * W;

    __shared__ int   s_cell[NT];
    __shared__ int   s_cls[NT];
    __shared__ int   s_wcell[NT];
    __shared__ int   s_wcls[NT];
    __shared__ int   s_cnt[2];
    __shared__ float s_wavesum[4];

    const int tid  = threadIdx.x;
    const int wave = tid >> 6;
    const int lane = tid & 63;

    // ---- Phase 1a: per-target cell/class ----
    if (tid < NT) {
        const float* tg = targets + ((size_t)b * NT + tid) * 5;
        float c  = tg[0];
        float x  = tg[1];
        float y  = tg[2];
        float z3 = tg[3];
        float z4 = tg[4];
        bool valid = (c != 0.0f) || (x != 0.0f) || (y != 0.0f) ||
                     (z3 != 0.0f) || (z4 != 0.0f);
        int cell = -1, cls = 0;
        if (valid) {
            int row = (int)(y * (float)H);   // trunc == .astype(int32)
            int col = (int)(x * (float)W);
            cell = row * W + col;
            cls  = (int)c;
        }
        s_cell[tid] = cell;
        s_cls[tid]  = cls;
    }
    __syncthreads();

    // ---- Phase 1b: parallel last-write-wins + ballot compaction ----
    int  mycell = (tid < NT) ? s_cell[tid] : -1;
    bool win    = (tid < NT) && (mycell >= 0);
    #pragma unroll 4
    for (int u = 0; u < NT; ++u) {
        int cu = s_cell[u];
        win = win && !((u > tid) && (cu == mycell));
    }
    unsigned long long m = __ballot(win);
    if (wave < 2 && lane == 0) s_cnt[wave] = __popcll(m);
    __syncthreads();

    if (win) {
        int pos = __popcll(m & ((1ull << lane) - 1ull));
        if (wave == 1) pos += s_cnt[0];
        s_wcell[pos] = mycell;
        s_wcls[pos]  = s_cls[tid];
    }
    __syncthreads();

    const int n      = s_cnt[0] + s_cnt[1];
    const int ntasks = n * NA;                 // denom (same for every chunk)
    const int gw     = chunk * 4 + wave;       // global wave slot: 0..31

    // ---- Phase 2: one wave per (cell, anchor) task; 80-wide log-softmax ----
    float acc = 0.0f;
    for (int task = gw; task < ntasks; task += 4 * CH) {
        int wi   = task / NA;
        int a    = task - wi * NA;
        int cell = s_wcell[wi];
        int cls  = s_wcls[wi];

        // gt_flat index i in (H, W, A) order:
        int i = cell * NA + a;
        // pred row i interpreted in (A, H, W) order (reference's pairing bug):
        int a2  = i / HW;
        int rem = i - a2 * HW;
        int h2  = rem / W;
        int w2  = rem - h2 * W;

        const float* base =
            out + ((((size_t)b * NA + a2) * H + h2) * (size_t)W + w2) * (5 + NC) + 5;

        float x0 = base[lane];
        float x1 = (lane < 16) ? base[64 + lane] : -INFINITY;

        float mx = fmaxf(x0, x1);
        #pragma unroll
        for (int off = 32; off; off >>= 1) mx = fmaxf(mx, __shfl_xor(mx, off));

        float e = __builtin_expf(x0 - mx) +
                  ((lane < 16) ? __builtin_expf(x1 - mx) : 0.0f);
        #pragma unroll
        for (int off = 32; off; off >>= 1) e += __shfl_xor(e, off);

        float logsum = mx + __builtin_logf(e);

        float xt = (cls < 64) ? __shfl(x0, cls) : __shfl(x1, cls - 64);
        acc += (logsum - xt);   // nll; identical on every lane
    }

    if (lane == 0) s_wavesum[wave] = acc;
    __syncthreads();

    if (tid == 0) {
        float total = s_wavesum[0] + s_wavesum[1] + s_wavesum[2] + s_wavesum[3];
        int denom = ntasks > 0 ? ntasks : 1;
        partials[blockIdx.x] = total / (float)denom;
    }
}

// Deterministic fixed-tree reduction of the 384 partials.
__global__ __launch_bounds__(128) void reduce_kernel(
    const float* __restrict__ partials, float* __restrict__ out)
{
    __shared__ float sm[128];
    const int tid = threadIdx.x;
    float a = partials[tid] + partials[tid + 128] + partials[tid + 256];
    sm[tid] = a;
    __syncthreads();
    #pragma unroll
    for (int off = 64; off; off >>= 1) {
        if (tid < off) sm[tid] += sm[tid + off];
        __syncthreads();
    }
    if (tid == 0) out[0] = sm[0] / (float)NB;
}

extern "C" void kernel_launch(void* const* d_in, const int* in_sizes, int n_in,
                              void* d_out, int out_size, void* d_ws, size_t ws_size,
                              hipStream_t stream) {
    const float* out0    = (const float*)d_in[0];
    const float* out1    = (const float*)d_in[1];
    const float* out2    = (const float*)d_in[2];
    const float* targets = (const float*)d_in[3];

    float* partials = (float*)d_ws;   // NPART floats
    float* loss     = (float*)d_out;  // 1 float

    class_loss_kernel<<<NPART, 256, 0, stream>>>(out0, out1, out2, targets, partials);
    reduce_kernel<<<1, 128, 0, stream>>>(partials, loss);
}

// Round 3
// 18.996 us; speedup vs baseline: 13.0974x; 1.0773x over previous
//
#include <hip/hip_runtime.h>
#include <math.h>

#define NT 100
#define NA 3
#define NC 80
#define NSCALE 3
#define NB 16
#define BPB 38                       // blocks per (batch,scale): 152 waves, 300 tasks
#define NBLK (NB * NSCALE * BPB)     // 1824 blocks

// One wave handles up to 2 (target, anchor) tasks. Loads are issued
// speculatively right after cell indices are known; the duplicate-cell scan
// (last-write-wins) runs while loads are in flight and only gates the
// accumulation.
__global__ __launch_bounds__(256) void class_loss_kernel(
    const float* __restrict__ out0,
    const float* __restrict__ out1,
    const float* __restrict__ out2,
    const float* __restrict__ targets,
    float* __restrict__ partials)
{
    const int bs = blockIdx.x / BPB;     // 0..47
    const int j  = blockIdx.x % BPB;
    const int b = bs / NSCALE;
    const int s = bs % NSCALE;

    const float* out; int H;
    if (s == 0)      { out = out0; H = 128; }
    else if (s == 1) { out = out1; H = 64;  }
    else             { out = out2; H = 32;  }
    const int W = H, HW = H * W;

    __shared__ int s_cell[NT];
    __shared__ int s_cls[NT];
    __shared__ unsigned long long s_mask[2];
    __shared__ float s_wavesum[4];

    const int tid  = threadIdx.x;
    const int wave = tid >> 6;
    const int lane = tid & 63;

    // ---- per-target cell/class ----
    if (tid < NT) {
        const float* tg = targets + ((size_t)b * NT + tid) * 5;
        float c = tg[0], x = tg[1], y = tg[2], z3 = tg[3], z4 = tg[4];
        bool valid = (c != 0.f) || (x != 0.f) || (y != 0.f) ||
                     (z3 != 0.f) || (z4 != 0.f);
        int cell = -1, cls = 0;
        if (valid) {
            cell = (int)(y * (float)H) * W + (int)(x * (float)W);  // trunc
            cls  = (int)c;
        }
        s_cell[tid] = cell;
        s_cls[tid]  = cls;
    }
    __syncthreads();

    // ---- this wave's two task slots: task = wi*NA + a over targets ----
    const int t0 = j * 4 + wave;          // < 152, always a real slot
    const int t1 = t0 + 4 * BPB;          // may be >= 300
    const bool have1 = (t1 < NT * NA);

    const int wi0 = t0 / NA, a0 = t0 - wi0 * NA;
    const int wi1 = have1 ? (t1 / NA) : 0;
    const int a1  = have1 ? (t1 - wi1 * NA) : 0;

    const int cell0 = s_cell[wi0], cls0 = s_cls[wi0];
    const int cell1 = s_cell[wi1], cls1 = s_cls[wi1];

    // gt_flat index i in (H,W,A) order; pred row i read in (A,H,W) order
    // (faithful to the reference's pairing). Clamp invalid cells to 0 so the
    // speculative load address is always in-bounds.
    const int c0 = (cell0 >= 0) ? cell0 : 0;
    const int i0 = c0 * NA + a0;
    const int A0 = i0 / HW, r0 = i0 - A0 * HW;
    const float* base0 = out + (((size_t)b * NA + A0) * HW + r0) * (5 + NC) + 5;

    const int c1 = (cell1 >= 0) ? cell1 : 0;
    const int i1 = c1 * NA + a1;
    const int A1 = i1 / HW, r1 = i1 - A1 * HW;
    const float* base1 = out + (((size_t)b * NA + A1) * HW + r1) * (5 + NC) + 5;

    // ---- speculative loads (in flight during the dedup scan) ----
    float x00 = base0[lane];
    float x01 = (lane < 16) ? base0[64 + lane] : -INFINITY;
    float x10 = base1[lane];
    float x11 = (lane < 16) ? base1[64 + lane] : -INFINITY;

    // ---- last-write-wins scan + ballot (overlaps load latency) ----
    int  mycell = (tid < NT) ? s_cell[tid] : -1;
    bool win    = (mycell >= 0);
    #pragma unroll 4
    for (int u = 0; u < NT; ++u) {
        int cu = s_cell[u];
        if (u > tid && cu == mycell) win = false;
    }
    unsigned long long mb = __ballot(win);
    if (wave < 2 && lane == 0) s_mask[wave] = mb;
    __syncthreads();

    const unsigned long long m0 = s_mask[0], m1 = s_mask[1];
    const int n = __popcll(m0) + __popcll(m1);           // winners (>=1)
    const bool w0 = (wi0 < 64) ? ((m0 >> wi0) & 1ull) : ((m1 >> (wi0 - 64)) & 1ull);
    const bool w1 = (wi1 < 64) ? ((m0 >> wi1) & 1ull) : ((m1 >> (wi1 - 64)) & 1ull);

    float acc = 0.0f;
    {   // task 0
        float mx = fmaxf(x00, x01);
        #pragma unroll
        for (int off = 32; off; off >>= 1) mx = fmaxf(mx, __shfl_xor(mx, off));
        float e = __builtin_expf(x00 - mx) +
                  ((lane < 16) ? __builtin_expf(x01 - mx) : 0.0f);
        #pragma unroll
        for (int off = 32; off; off >>= 1) e += __shfl_xor(e, off);
        float logsum = mx + __builtin_logf(e);
        float xt = (cls0 < 64) ? __shfl(x00, cls0) : __shfl(x01, cls0 - 64);
        if (cell0 >= 0 && w0) acc += (logsum - xt);
    }
    if (have1) {   // task 1 (wave-uniform guard)
        float mx = fmaxf(x10, x11);
        #pragma unroll
        for (int off = 32; off; off >>= 1) mx = fmaxf(mx, __shfl_xor(mx, off));
        float e = __builtin_expf(x10 - mx) +
                  ((lane < 16) ? __builtin_expf(x11 - mx) : 0.0f);
        #pragma unroll
        for (int off = 32; off; off >>= 1) e += __shfl_xor(e, off);
        float logsum = mx + __builtin_logf(e);
        float xt = (cls1 < 64) ? __shfl(x10, cls1) : __shfl(x11, cls1 - 64);
        if (cell1 >= 0 && w1) acc += (logsum - xt);
    }

    if (lane == 0) s_wavesum[wave] = acc;
    __syncthreads();

    if (tid == 0) {
        float total = s_wavesum[0] + s_wavesum[1] + s_wavesum[2] + s_wavesum[3];
        partials[blockIdx.x] = total / (float)(n * NA);
    }
}

// Deterministic fixed-tree reduction of the NBLK partials.
__global__ __launch_bounds__(256) void reduce_kernel(
    const float* __restrict__ partials, float* __restrict__ out)
{
    __shared__ float sm[256];
    const int tid = threadIdx.x;
    float a = 0.0f;
    #pragma unroll
    for (int k = 0; k < (NBLK + 255) / 256; ++k) {
        int idx = tid + k * 256;
        if (idx < NBLK) a += partials[idx];
    }
    sm[tid] = a;
    __syncthreads();
    #pragma unroll
    for (int off = 128; off; off >>= 1) {
        if (tid < off) sm[tid] += sm[tid + off];
        __syncthreads();
    }
    if (tid == 0) out[0] = sm[0] / (float)NB;
}

extern "C" void kernel_launch(void* const* d_in, const int* in_sizes, int n_in,
                              void* d_out, int out_size, void* d_ws, size_t ws_size,
                              hipStream_t stream) {
    const float* out0    = (const float*)d_in[0];
    const float* out1    = (const float*)d_in[1];
    const float* out2    = (const float*)d_in[2];
    const float* targets = (const float*)d_in[3];

    float* partials = (float*)d_ws;   // NBLK floats
    float* loss     = (float*)d_out;  // 1 float

    class_loss_kernel<<<NBLK, 256, 0, stream>>>(out0, out1, out2, targets, partials);
    reduce_kernel<<<1, 256, 0, stream>>>(partials, loss);
}